// Round 10
// baseline (346.518 us; speedup 1.0000x reference)
//
#include <hip/hip_runtime.h>
#include <stdint.h>

#define D 2048
#define R 64
#define M_TOTAL 8192

typedef float f32x4 __attribute__((ext_vector_type(4)));
typedef __bf16 bf16x8 __attribute__((ext_vector_type(8)));
typedef unsigned short u16x8 __attribute__((ext_vector_type(8)));
typedef unsigned short u16x4 __attribute__((ext_vector_type(4)));

__device__ __forceinline__ unsigned short f2bf(float f) {
  unsigned u = __builtin_bit_cast(unsigned, f);
  u += 0x7FFFu + ((u >> 16) & 1u);
  return (unsigned short)(u >> 16);
}

__device__ __forceinline__ u16x8 pack8(float4 a, float4 b) {
  u16x8 o = { f2bf(a.x), f2bf(a.y), f2bf(a.z), f2bf(a.w),
              f2bf(b.x), f2bf(b.y), f2bf(b.z), f2bf(b.w) };
  return o;
}

__device__ __forceinline__ void gload_lds16(const void* g, void* l) {
  __builtin_amdgcn_global_load_lds(
      (const __attribute__((address_space(1))) void*)g,
      (__attribute__((address_space(3))) void*)l, 16, 0, 0);
}

// ---------------- fused prep (512 threads/block) ----------------
__global__ __launch_bounds__(512) void prep_kernel(
    const float* __restrict__ x, const float* __restrict__ A,
    const float* __restrict__ B, const float* __restrict__ C,
    const float* __restrict__ w1, const float* __restrict__ b1,
    const float* __restrict__ w2,
    unsigned short* __restrict__ xbf, unsigned short* __restrict__ st,
    unsigned short* __restrict__ w2bf, unsigned short* __restrict__ hbf) {
  __shared__ unsigned short plds[24576];  // 48 KB shared by roles
  const int t = threadIdx.x;
  const int bx = blockIdx.x;

  if (bx < 256) {
    // ---- h + x-conv ----
    unsigned short* sX = plds;         // [4 kq][2 buf][32 rows][32 k] = 16 KB
    unsigned short* sW = plds + 8192;  // [4 kq][2 buf][64 rows][32 k] = 32 KB
    const int m0 = bx * 32;
    const int kq = t >> 7, u = t & 127;
    const int row = u >> 2, c = u & 3;
    const int row_w = u >> 1, cw0 = (u & 1) * 2;
    const float* xp = x + (size_t)(m0 + row) * D + kq * 512 + c * 8;
    const float* wp = w1 + (size_t)row_w * D + kq * 512 + cw0 * 8;
    unsigned short* xw = xbf + (size_t)(m0 + row) * D + kq * 512 + c * 8;
    unsigned short* sXw = sX + kq * 2048 + row * 32 + (c ^ ((row >> 1) & 3)) * 8;
    const int rw2 = (row_w >> 1) & 3;
    unsigned short* sWw0 = sW + kq * 4096 + row_w * 32 + (cw0 ^ rw2) * 8;
    unsigned short* sWw1 = sW + kq * 4096 + row_w * 32 + ((cw0 + 1) ^ rw2) * 8;
    const int w = t >> 6, l = t & 63, lm = l & 15, lk = l >> 4;
    const int kqw = w >> 1, rg = w & 1;
    const int rslot = (lk ^ ((lm >> 1) & 3)) * 8;
    const unsigned short* sXr = sX + kqw * 2048 + (rg * 16 + lm) * 32 + rslot;
    const unsigned short* sWr = sW + kqw * 4096 + lm * 32 + rslot;

    f32x4 acc[4] = {};
    float4 qx[2][2], qw[2][4];
#define HLOADX(P, KT) do { qx[P][0] = *(const float4*)(xp + (KT) * 32); \
                           qx[P][1] = *(const float4*)(xp + (KT) * 32 + 4); } while (0)
#define HLOADW(P, KT) do { qw[P][0] = *(const float4*)(wp + (KT) * 32); \
                           qw[P][1] = *(const float4*)(wp + (KT) * 32 + 4); \
                           qw[P][2] = *(const float4*)(wp + (KT) * 32 + 8); \
                           qw[P][3] = *(const float4*)(wp + (KT) * 32 + 12); } while (0)
    HLOADX(0, 0); HLOADW(0, 0); HLOADX(1, 1); HLOADW(1, 1);
#define HSTEP(P, KT) do { \
    u16x8 ox = pack8(qx[P][0], qx[P][1]); \
    *(u16x8*)(sXw + (P) * 1024) = ox; \
    *(u16x8*)(xw + (KT) * 32) = ox; \
    *(u16x8*)(sWw0 + (P) * 2048) = pack8(qw[P][0], qw[P][1]); \
    *(u16x8*)(sWw1 + (P) * 2048) = pack8(qw[P][2], qw[P][3]); \
    if ((KT) + 2 < 16) { HLOADX(P, (KT) + 2); HLOADW(P, (KT) + 2); } \
    __syncthreads(); \
    { bf16x8 a_ = __builtin_bit_cast(bf16x8, *(const u16x8*)(sXr + (P) * 1024)); \
      _Pragma("unroll") \
      for (int j = 0; j < 4; ++j) { \
        bf16x8 b_ = __builtin_bit_cast(bf16x8, *(const u16x8*)(sWr + (P) * 2048 + j * 512)); \
        acc[j] = __builtin_amdgcn_mfma_f32_16x16x32_bf16(a_, b_, acc[j], 0, 0, 0); \
      } } } while (0)
#pragma unroll 1
    for (int it = 0; it < 8; ++it) { HSTEP(0, it * 2); HSTEP(1, it * 2 + 1); }
#undef HSTEP
#undef HLOADX
#undef HLOADW

    __syncthreads();
    float* red = (float*)plds;
    if (kqw > 0) {
#pragma unroll
      for (int j = 0; j < 4; ++j)
        *(f32x4*)(red + (((((kqw - 1) * 2 + rg) * 4) + j) * 64 + l) * 4) = acc[j];
    }
    __syncthreads();
    if (kqw == 0) {
      int m_base = m0 + rg * 16 + lk * 4;
#pragma unroll
      for (int j = 0; j < 4; ++j) {
        f32x4 s = acc[j];
#pragma unroll
        for (int q = 1; q < 4; ++q)
          s += *(const f32x4*)(red + (((((q - 1) * 2 + rg) * 4) + j) * 64 + l) * 4);
        int n = j * 16 + lm;
        float bv = b1[n];
#pragma unroll
        for (int r = 0; r < 4; ++r) {
          float v = s[r] + bv;
          float g = 0.5f * v * (1.0f + erff(v * 0.70710678118654752f));
          hbf[(size_t)(m_base + r) * R + n] = f2bf(g);
        }
      }
    }
  } else if (bx < 768) {
    // ---- sumt: 128(k) x 64(n) tiles ----
    unsigned short (*lds)[68] = (unsigned short(*)[68])plds;
    const int id = bx - 256;
    const int k0 = (id >> 5) * 128, n0 = (id & 31) * 64;
#pragma unroll
    for (int q = 0; q < 4; ++q) {
      int rowq = q * 32 + (t >> 4);
      int col = (t & 15) * 4;
      size_t off = (size_t)(k0 + rowq) * D + n0 + col;
      float4 a = *(const float4*)(A + off);
      float4 b = *(const float4*)(B + off);
      float4 cc = *(const float4*)(C + off);
      u16x4 o = { f2bf(a.x + b.x + cc.x), f2bf(a.y + b.y + cc.y),
                  f2bf(a.z + b.z + cc.z), f2bf(a.w + b.w + cc.w) };
      *(u16x4*)(&lds[rowq][col]) = o;
    }
    __syncthreads();
    const int n = t >> 3, kc = (t & 7) * 16;
    u16x8 v0, v1;
#pragma unroll
    for (int jj = 0; jj < 8; ++jj) v0[jj] = lds[kc + jj][n];
#pragma unroll
    for (int jj = 0; jj < 8; ++jj) v1[jj] = lds[kc + 8 + jj][n];
    size_t ooff = (size_t)(n0 + n) * D + k0 + kc;
    *(u16x8*)(st + ooff) = v0;
    *(u16x8*)(st + ooff + 8) = v1;
  } else {
    // ---- W2 conv ----
    const int NW4 = (D * R) / 4;  // 32768
    for (int i = (bx - 768) * 512 + t; i < NW4; i += 4 * 512) {
      float4 v = ((const float4*)w2)[i];
      u16x4 o = { f2bf(v.x), f2bf(v.y), f2bf(v.z), f2bf(v.w) };
      *(u16x4*)(w2bf + (size_t)i * 4) = o;
    }
  }
}

// ---------------- main gemm, templated for ablation ----------------
// V=0: real kernel (= R9). V=3: reads+MFMA+barriers, NO in-loop staging/vmcnt.
// V=4: MFMA+barriers only (operands loaded once). V!=0 writes to scratch with
// row-masked addresses; REP repeats the K-loop to keep diagnostics in top-5.
template <int V, int REP>
__global__ __launch_bounds__(512, 2) void gemm_kernel(
    const unsigned short* __restrict__ xbf, const unsigned short* __restrict__ st,
    const unsigned short* __restrict__ hbf, const unsigned short* __restrict__ w2bf,
    const float* __restrict__ b2, const float* __restrict__ dp,
    float* __restrict__ out) {
  constexpr bool DO_READS = (V == 0 || V == 3);
  constexpr bool DO_STAGE = (V == 0 || V == 2);
  __shared__ unsigned short sA[2 * 16384];
  __shared__ unsigned short sB[2 * 16384];
  const int tid = threadIdx.x;
  const int w = tid >> 6, l = tid & 63, lk = l >> 4, lm = l & 15;
  const int wm = w >> 2, wn = w & 3;
  int bid = blockIdx.x;
  int wg = (bid & 7) * 32 + (bid >> 3);
  int mb = wg >> 3, nb = wg & 7;
  int m0 = mb * 256, n0 = nb * 256;

  const int kg = (tid & 7) ^ ((tid >> 3) & 7);
  const unsigned short* gA = xbf + (size_t)(m0 + (tid >> 3)) * D + kg * 8;
  const unsigned short* gB = st + (size_t)(n0 + (tid >> 3)) * D + kg * 8;
  const int dstw = w * 512;

  const int s7 = lm & 7;
  const int gsw0 = (lk ^ s7) * 8;
  const int gsw1 = ((4 | lk) ^ s7) * 8;
  const int arow = (wm * 128 + lm) * 64;
  const int brow = (wn * 64 + lm) * 64;

  const int NT = D / 64;  // 32
  f32x4 acc[8][4] = {};
  bf16x8 aA[4][2], aB[4][2], bt[2][2], be[2][2], bo[2][2];

#define BUFA(S) (sA + (S) * 16384)
#define BUFB(S) (sB + (S) * 16384)
#define LD8(buf, off) __builtin_bit_cast(bf16x8, *(const u16x8*)((buf) + (off)))
#define SB0() __builtin_amdgcn_sched_barrier(0)
#define BAR() __builtin_amdgcn_s_barrier()
#define LGKM4() asm volatile("s_waitcnt lgkmcnt(4)" ::: "memory")
#define LGKM8() asm volatile("s_waitcnt lgkmcnt(8)" ::: "memory")

#define STAGE2(gptr, sbuf, T, h, S) do { if ((T) < NT) { \
    const unsigned short* g_ = (gptr) + (size_t)((h) * 128) * D + (T) * 64; \
    unsigned short* d_ = (sbuf) + ((S) * 16384 + (h) * 8192 + dstw); \
    gload_lds16(g_, d_); \
    gload_lds16(g_ + 64 * D, d_ + 4096); } } while (0)

#define RD_A03(S) do { _Pragma("unroll") for (int i = 0; i < 4; ++i) { \
    aA[i][0] = LD8(BUFA(S), arow + i * 1024 + gsw0); \
    aA[i][1] = LD8(BUFA(S), arow + i * 1024 + gsw1); } } while (0)
#define RD_A47(S) do { _Pragma("unroll") for (int i = 0; i < 4; ++i) { \
    aB[i][0] = LD8(BUFA(S), arow + (i + 4) * 1024 + gsw0); \
    aB[i][1] = LD8(BUFA(S), arow + (i + 4) * 1024 + gsw1); } } while (0)
#define RD_B23(S) do { _Pragma("unroll") for (int j = 0; j < 2; ++j) { \
    bt[j][0] = LD8(BUFB(S), brow + (j + 2) * 1024 + gsw0); \
    bt[j][1] = LD8(BUFB(S), brow + (j + 2) * 1024 + gsw1); } } while (0)
#define RD_B01(S, DST) do { _Pragma("unroll") for (int j = 0; j < 2; ++j) { \
    DST[j][0] = LD8(BUFB(S), brow + j * 1024 + gsw0); \
    DST[j][1] = LD8(BUFB(S), brow + j * 1024 + gsw1); } } while (0)

#define QUAD(AR, BR, IO, JO) do { \
    __builtin_amdgcn_s_setprio(1); \
    _Pragma("unroll") for (int i = 0; i < 4; ++i) \
    _Pragma("unroll") for (int j = 0; j < 2; ++j) { \
      acc[i + IO][j + JO] = __builtin_amdgcn_mfma_f32_16x16x32_bf16(AR[i][0], BR[j][0], acc[i + IO][j + JO], 0, 0, 0); \
      acc[i + IO][j + JO] = __builtin_amdgcn_mfma_f32_16x16x32_bf16(AR[i][1], BR[j][1], acc[i + IO][j + JO], 0, 0, 0); \
    } \
    __builtin_amdgcn_s_setprio(0); } while (0)

#define TILE(S, BCUR, BNXT, KT) do { \
    if constexpr (DO_READS) RD_B23(S); \
    if constexpr (DO_STAGE) STAGE2(gB, sB, (KT) + 2, 0, S); \
    SB0(); BAR(); if constexpr (DO_READS) { LGKM4(); } SB0(); \
    QUAD(aA, BCUR, 0, 0); \
    SB0(); BAR(); \
    if constexpr (DO_READS) RD_A47(S); \
    if constexpr (DO_STAGE) STAGE2(gA, sA, (KT) + 2, 0, S); \
    SB0(); BAR(); if constexpr (DO_READS) { LGKM8(); } SB0(); \
    QUAD(aA, bt, 0, 2); \
    SB0(); BAR(); \
    if constexpr (DO_READS) RD_A03((S) ^ 1); \
    if constexpr (DO_STAGE) STAGE2(gB, sB, (KT) + 2, 1, S); \
    SB0(); BAR(); if constexpr (DO_READS) { LGKM8(); } SB0(); \
    QUAD(aB, bt, 4, 2); \
    SB0(); BAR(); \
    if constexpr (DO_READS) RD_B01((S) ^ 1, BNXT); \
    if constexpr (DO_STAGE) STAGE2(gA, sA, (KT) + 2, 1, S); \
    if constexpr (DO_STAGE) { \
      if ((KT) < NT - 2) asm volatile("s_waitcnt vmcnt(4)" ::: "memory"); \
      else               asm volatile("s_waitcnt vmcnt(0)" ::: "memory"); \
    } \
    SB0(); BAR(); if constexpr (DO_READS) { LGKM4(); } SB0(); \
    QUAD(aB, BCUR, 4, 0); \
    SB0(); BAR(); } while (0)

  // prologue: stage tiles 0 and 1; drain all but newest half; pre-read
  STAGE2(gB, sB, 0, 0, 0); STAGE2(gA, sA, 0, 0, 0);
  STAGE2(gB, sB, 0, 1, 0); STAGE2(gA, sA, 0, 1, 0);
  STAGE2(gB, sB, 1, 0, 1); STAGE2(gA, sA, 1, 0, 1);
  STAGE2(gB, sB, 1, 1, 1); STAGE2(gA, sA, 1, 1, 1);
  if constexpr (V == 0) asm volatile("s_waitcnt vmcnt(2)" ::: "memory");
  else                  asm volatile("s_waitcnt vmcnt(0)" ::: "memory");
  BAR();
  RD_A03(0);
  RD_B01(0, be);
  if constexpr (!DO_READS) {  // V4/V2: fixed operands for the whole loop
    RD_B23(0); RD_A47(0); RD_B01(1, bo);
    asm volatile("s_waitcnt lgkmcnt(0)" ::: "memory");
  }
  SB0();

#pragma unroll 1
  for (int rep = 0; rep < REP; ++rep) {
#pragma unroll 1
    for (int it = 0; it < NT / 2; ++it) {
      const int kt0 = it * 2;
      TILE(0, be, bo, kt0);
      TILE(1, bo, be, kt0 + 1);
    }
  }

  // epilogue: dt = h @ W2^T + b2 (rank-64), out = acc*dt + Dp
  bf16x8 wb0[4], wb1[4];
  float b2v[4], dpv[4];
#pragma unroll
  for (int j = 0; j < 4; ++j) {
    int n = n0 + wn * 64 + j * 16 + lm;
    const u16x8* wp = (const u16x8*)(w2bf + (size_t)n * R + lk * 8);
    wb0[j] = __builtin_bit_cast(bf16x8, wp[0]);
    wb1[j] = __builtin_bit_cast(bf16x8, wp[4]);
    b2v[j] = b2[n];
    dpv[j] = dp[n];
  }
#pragma unroll
  for (int mi = 0; mi < 8; ++mi) {
    int hrow = m0 + wm * 128 + mi * 16 + lm;
    const u16x8* hp = (const u16x8*)(hbf + (size_t)hrow * R + lk * 8);
    bf16x8 ha0 = __builtin_bit_cast(bf16x8, hp[0]);
    bf16x8 ha1 = __builtin_bit_cast(bf16x8, hp[4]);
    int mbase = m0 + wm * 128 + mi * 16 + lk * 4;
#pragma unroll
    for (int j = 0; j < 4; ++j) {
      f32x4 dt = {};
      dt = __builtin_amdgcn_mfma_f32_16x16x32_bf16(ha0, wb0[j], dt, 0, 0, 0);
      dt = __builtin_amdgcn_mfma_f32_16x16x32_bf16(ha1, wb1[j], dt, 0, 0, 0);
      int n = n0 + wn * 64 + j * 16 + lm;
#pragma unroll
      for (int r = 0; r < 4; ++r) {
        float val = acc[mi][j][r] * (dt[r] + b2v[j]) + dpv[j];
        int rowi = mbase + r;
        if constexpr (V != 0) rowi &= 2047;  // scratch: stay within 16 MB
        out[(size_t)rowi * D + n] = val;
      }
    }
  }
#undef TILE
#undef QUAD
#undef RD_A03
#undef RD_A47
#undef RD_B23
#undef RD_B01
#undef STAGE2
#undef LGKM4
#undef LGKM8
#undef BAR
#undef SB0
#undef LD8
#undef BUFA
#undef BUFB
}

extern "C" void kernel_launch(void* const* d_in, const int* in_sizes, int n_in,
                              void* d_out, int out_size, void* d_ws, size_t ws_size,
                              hipStream_t stream) {
  const float* x  = (const float*)d_in[0];
  const float* A  = (const float*)d_in[1];
  const float* B  = (const float*)d_in[2];
  const float* C  = (const float*)d_in[3];
  const float* Dp = (const float*)d_in[4];
  const float* W1 = (const float*)d_in[5];
  const float* b1 = (const float*)d_in[6];
  const float* W2 = (const float*)d_in[7];
  const float* b2 = (const float*)d_in[8];
  float* out = (float*)d_out;

  uint8_t* ws = (uint8_t*)d_ws;
  unsigned short* xbf  = (unsigned short*)ws;                                // 32 MB
  unsigned short* st   = (unsigned short*)(ws + (32u << 20));                // 8 MB
  unsigned short* w2bf = (unsigned short*)(ws + (40u << 20));                // 256 KB
  unsigned short* hbf  = (unsigned short*)(ws + (41u << 20));                // 1 MB

  prep_kernel<<<772, 512, 0, stream>>>(x, A, B, C, W1, b1, W2, xbf, st, w2bf, hbf);
  // real output
  gemm_kernel<0, 1><<<256, 512, 0, stream>>>(xbf, st, hbf, w2bf, b2, Dp, out);
  // ablation diagnostics -> scratch (xbf region; prep fully rewrites it each call)
  gemm_kernel<3, 3><<<256, 512, 0, stream>>>(xbf, st, hbf, w2bf, b2, Dp, (float*)xbf);
  gemm_kernel<4, 3><<<256, 512, 0, stream>>>(xbf, st, hbf, w2bf, b2, Dp, (float*)xbf);
}

// Round 11
// 98.408 us; speedup vs baseline: 3.5212x; 3.5212x over previous
//
#include <hip/hip_runtime.h>
#include <stdint.h>

#define D 2048
#define R 64
#define M_TOTAL 8192

typedef float f32x4 __attribute__((ext_vector_type(4)));
typedef __bf16 bf16x8 __attribute__((ext_vector_type(8)));
typedef unsigned short u16x8 __attribute__((ext_vector_type(8)));
typedef unsigned short u16x4 __attribute__((ext_vector_type(4)));

__device__ __forceinline__ unsigned short f2bf(float f) {
  unsigned u = __builtin_bit_cast(unsigned, f);
  u += 0x7FFFu + ((u >> 16) & 1u);
  return (unsigned short)(u >> 16);
}

__device__ __forceinline__ u16x8 pack8(float4 a, float4 b) {
  u16x8 o = { f2bf(a.x), f2bf(a.y), f2bf(a.z), f2bf(a.w),
              f2bf(b.x), f2bf(b.y), f2bf(b.z), f2bf(b.w) };
  return o;
}

__device__ __forceinline__ void gload_lds16(const void* g, void* l) {
  __builtin_amdgcn_global_load_lds(
      (const __attribute__((address_space(1))) void*)g,
      (__attribute__((address_space(3))) void*)l, 16, 0, 0);
}

// Inline-asm global->LDS staging: NOT tracked by the compiler's waitcnt
// hazard pass, so no hidden vmcnt(0) drains get inserted around ds_reads.
// M0 = wave-uniform LDS byte offset (readfirstlane'd by caller).
__device__ __forceinline__ void gload_lds_asm(const unsigned short* g, int lds_byte) {
  asm volatile("s_mov_b32 m0, %1\n\t"
               "global_load_lds_dwordx4 %0, off"
               :: "v"(g), "s"(lds_byte)
               : "memory");
}

__device__ __forceinline__ int lds_addr(const void* p) {
  return (int)(size_t)(const __attribute__((address_space(3))) void*)p;
}

// ---------------- fused prep (512 threads/block) ----------------
// blocks 0..255  : h = bf16(gelu(x@W1^T+b1)) from f32 x, ALSO writes xbf.
// blocks 256..767: St[n][k] = bf16(A[k][n]+B[k][n]+C[k][n]), 128x64 tiles.
// blocks 768..771: W2 f32->bf16.
__global__ __launch_bounds__(512) void prep_kernel(
    const float* __restrict__ x, const float* __restrict__ A,
    const float* __restrict__ B, const float* __restrict__ C,
    const float* __restrict__ w1, const float* __restrict__ b1,
    const float* __restrict__ w2,
    unsigned short* __restrict__ xbf, unsigned short* __restrict__ st,
    unsigned short* __restrict__ w2bf, unsigned short* __restrict__ hbf) {
  __shared__ unsigned short plds[24576];  // 48 KB shared by roles
  const int t = threadIdx.x;
  const int bx = blockIdx.x;

  if (bx < 256) {
    // ---- h + x-conv ----
    unsigned short* sX = plds;         // [4 kq][2 buf][32 rows][32 k] = 16 KB
    unsigned short* sW = plds + 8192;  // [4 kq][2 buf][64 rows][32 k] = 32 KB
    const int m0 = bx * 32;
    const int kq = t >> 7, u = t & 127;
    const int row = u >> 2, c = u & 3;
    const int row_w = u >> 1, cw0 = (u & 1) * 2;
    const float* xp = x + (size_t)(m0 + row) * D + kq * 512 + c * 8;
    const float* wp = w1 + (size_t)row_w * D + kq * 512 + cw0 * 8;
    unsigned short* xw = xbf + (size_t)(m0 + row) * D + kq * 512 + c * 8;
    unsigned short* sXw = sX + kq * 2048 + row * 32 + (c ^ ((row >> 1) & 3)) * 8;
    const int rw2 = (row_w >> 1) & 3;
    unsigned short* sWw0 = sW + kq * 4096 + row_w * 32 + (cw0 ^ rw2) * 8;
    unsigned short* sWw1 = sW + kq * 4096 + row_w * 32 + ((cw0 + 1) ^ rw2) * 8;
    const int w = t >> 6, l = t & 63, lm = l & 15, lk = l >> 4;
    const int kqw = w >> 1, rg = w & 1;
    const int rslot = (lk ^ ((lm >> 1) & 3)) * 8;
    const unsigned short* sXr = sX + kqw * 2048 + (rg * 16 + lm) * 32 + rslot;
    const unsigned short* sWr = sW + kqw * 4096 + lm * 32 + rslot;

    f32x4 acc[4] = {};
    float4 qx[2][2], qw[2][4];
#define HLOADX(P, KT) do { qx[P][0] = *(const float4*)(xp + (KT) * 32); \
                           qx[P][1] = *(const float4*)(xp + (KT) * 32 + 4); } while (0)
#define HLOADW(P, KT) do { qw[P][0] = *(const float4*)(wp + (KT) * 32); \
                           qw[P][1] = *(const float4*)(wp + (KT) * 32 + 4); \
                           qw[P][2] = *(const float4*)(wp + (KT) * 32 + 8); \
                           qw[P][3] = *(const float4*)(wp + (KT) * 32 + 12); } while (0)
    HLOADX(0, 0); HLOADW(0, 0); HLOADX(1, 1); HLOADW(1, 1);
#define HSTEP(P, KT) do { \
    u16x8 ox = pack8(qx[P][0], qx[P][1]); \
    *(u16x8*)(sXw + (P) * 1024) = ox; \
    *(u16x8*)(xw + (KT) * 32) = ox; \
    *(u16x8*)(sWw0 + (P) * 2048) = pack8(qw[P][0], qw[P][1]); \
    *(u16x8*)(sWw1 + (P) * 2048) = pack8(qw[P][2], qw[P][3]); \
    if ((KT) + 2 < 16) { HLOADX(P, (KT) + 2); HLOADW(P, (KT) + 2); } \
    __syncthreads(); \
    { bf16x8 a_ = __builtin_bit_cast(bf16x8, *(const u16x8*)(sXr + (P) * 1024)); \
      _Pragma("unroll") \
      for (int j = 0; j < 4; ++j) { \
        bf16x8 b_ = __builtin_bit_cast(bf16x8, *(const u16x8*)(sWr + (P) * 2048 + j * 512)); \
        acc[j] = __builtin_amdgcn_mfma_f32_16x16x32_bf16(a_, b_, acc[j], 0, 0, 0); \
      } } } while (0)
#pragma unroll 1
    for (int it = 0; it < 8; ++it) { HSTEP(0, it * 2); HSTEP(1, it * 2 + 1); }
#undef HSTEP
#undef HLOADX
#undef HLOADW

    __syncthreads();
    float* red = (float*)plds;
    if (kqw > 0) {
#pragma unroll
      for (int j = 0; j < 4; ++j)
        *(f32x4*)(red + (((((kqw - 1) * 2 + rg) * 4) + j) * 64 + l) * 4) = acc[j];
    }
    __syncthreads();
    if (kqw == 0) {
      int m_base = m0 + rg * 16 + lk * 4;
#pragma unroll
      for (int j = 0; j < 4; ++j) {
        f32x4 s = acc[j];
#pragma unroll
        for (int q = 1; q < 4; ++q)
          s += *(const f32x4*)(red + (((((q - 1) * 2 + rg) * 4) + j) * 64 + l) * 4);
        int n = j * 16 + lm;
        float bv = b1[n];
#pragma unroll
        for (int r = 0; r < 4; ++r) {
          float v = s[r] + bv;
          float g = 0.5f * v * (1.0f + erff(v * 0.70710678118654752f));
          hbf[(size_t)(m_base + r) * R + n] = f2bf(g);
        }
      }
    }
  } else if (bx < 768) {
    // ---- sumt: 128(k) x 64(n) tiles ----
    unsigned short (*lds)[68] = (unsigned short(*)[68])plds;
    const int id = bx - 256;
    const int k0 = (id >> 5) * 128, n0 = (id & 31) * 64;
#pragma unroll
    for (int q = 0; q < 4; ++q) {
      int rowq = q * 32 + (t >> 4);
      int col = (t & 15) * 4;
      size_t off = (size_t)(k0 + rowq) * D + n0 + col;
      float4 a = *(const float4*)(A + off);
      float4 b = *(const float4*)(B + off);
      float4 cc = *(const float4*)(C + off);
      u16x4 o = { f2bf(a.x + b.x + cc.x), f2bf(a.y + b.y + cc.y),
                  f2bf(a.z + b.z + cc.z), f2bf(a.w + b.w + cc.w) };
      *(u16x4*)(&lds[rowq][col]) = o;
    }
    __syncthreads();
    const int n = t >> 3, kc = (t & 7) * 16;
    u16x8 v0, v1;
#pragma unroll
    for (int jj = 0; jj < 8; ++jj) v0[jj] = lds[kc + jj][n];
#pragma unroll
    for (int jj = 0; jj < 8; ++jj) v1[jj] = lds[kc + 8 + jj][n];
    size_t ooff = (size_t)(n0 + n) * D + k0 + kc;
    *(u16x8*)(st + ooff) = v0;
    *(u16x8*)(st + ooff + 8) = v1;
  } else {
    // ---- W2 conv ----
    const int NW4 = (D * R) / 4;  // 32768
    for (int i = (bx - 768) * 512 + t; i < NW4; i += 4 * 512) {
      float4 v = ((const float4*)w2)[i];
      u16x4 o = { f2bf(v.x), f2bf(v.y), f2bf(v.z), f2bf(v.w) };
      *(u16x4*)(w2bf + (size_t)i * 4) = o;
    }
  }
}

// ---------------- main: out = (x @ S) * dt + Dp ----------------
// 256x256 tile, BK=64, 8 waves (2M x 4N). R9's 4-phase pipelined schedule
// (reads one phase ahead, counted lgkm waits) with staging emitted as
// INLINE-ASM global_load_lds_dwordx4 (untracked by compiler hazard pass ->
// no hidden vmcnt(0)). Single counted vmcnt(4) per tile at END OF P1:
// drains tile t+1's last-staged halves (distance >=2 phases) BEFORE P2
// reads tile t+1's A (closes R9's latent race); leaves tile t+2's 4 newest
// loads in flight. Tail tiles drain with vmcnt(0).
__global__ __launch_bounds__(512, 2) void gemm_kernel(
    const unsigned short* __restrict__ xbf, const unsigned short* __restrict__ st,
    const unsigned short* __restrict__ hbf, const unsigned short* __restrict__ w2bf,
    const float* __restrict__ b2, const float* __restrict__ dp,
    float* __restrict__ out) {
  __shared__ unsigned short sA[2 * 16384];  // 2 slots x 256 rows x 64 k, 64 KB
  __shared__ unsigned short sB[2 * 16384];  // 64 KB
  const int tid = threadIdx.x;
  const int w = tid >> 6, l = tid & 63, lk = l >> 4, lm = l & 15;
  const int wm = w >> 2, wn = w & 3;
  int bid = blockIdx.x;
  int wg = (bid & 7) * 32 + (bid >> 3);  // bijective XCD swizzle (256 wgs)
  int mb = wg >> 3, nb = wg & 7;
  int m0 = mb * 256, n0 = nb * 256;

  const int kg = (tid & 7) ^ ((tid >> 3) & 7);
  const unsigned short* gA = xbf + (size_t)(m0 + (tid >> 3)) * D + kg * 8;
  const unsigned short* gB = st + (size_t)(n0 + (tid >> 3)) * D + kg * 8;
  // wave-uniform LDS byte bases for staging (asm path)
  const int sAb = __builtin_amdgcn_readfirstlane(lds_addr(sA) + w * 1024);
  const int sBb = __builtin_amdgcn_readfirstlane(lds_addr(sB) + w * 1024);

  const int s7 = lm & 7;
  const int gsw0 = (lk ^ s7) * 8;        // kk=0
  const int gsw1 = ((4 | lk) ^ s7) * 8;  // kk=1
  const int arow = (wm * 128 + lm) * 64;
  const int brow = (wn * 64 + lm) * 64;

  const int NT = D / 64;  // 32
  f32x4 acc[8][4] = {};
  bf16x8 aA[4][2], aB[4][2], bt[2][2], be[2][2], bo[2][2];

#define BUFA(S) (sA + (S) * 16384)
#define BUFB(S) (sB + (S) * 16384)
#define LD8(buf, off) __builtin_bit_cast(bf16x8, *(const u16x8*)((buf) + (off)))
#define SB0() __builtin_amdgcn_sched_barrier(0)
#define BAR() __builtin_amdgcn_s_barrier()
#define LGKM4() asm volatile("s_waitcnt lgkmcnt(4)" ::: "memory")
#define LGKM8() asm volatile("s_waitcnt lgkmcnt(8)" ::: "memory")

// stage half-tile h of K-tile T into slot S (2 asm global_load_lds_dwordx4)
#define STAGE2(gptr, lbase, T, h, S) do { if ((T) < NT) { \
    const unsigned short* g_ = (gptr) + (size_t)((h) * 128) * D + (T) * 64; \
    int lb_ = (lbase) + (S) * 32768 + (h) * 16384; \
    gload_lds_asm(g_, lb_); \
    gload_lds_asm(g_ + 64 * D, lb_ + 8192); } } while (0)

#define RD_A03(S) do { _Pragma("unroll") for (int i = 0; i < 4; ++i) { \
    aA[i][0] = LD8(BUFA(S), arow + i * 1024 + gsw0); \
    aA[i][1] = LD8(BUFA(S), arow + i * 1024 + gsw1); } } while (0)
#define RD_A47(S) do { _Pragma("unroll") for (int i = 0; i < 4; ++i) { \
    aB[i][0] = LD8(BUFA(S), arow + (i + 4) * 1024 + gsw0); \
    aB[i][1] = LD8(BUFA(S), arow + (i + 4) * 1024 + gsw1); } } while (0)
#define RD_B23(S) do { _Pragma("unroll") for (int j = 0; j < 2; ++j) { \
    bt[j][0] = LD8(BUFB(S), brow + (j + 2) * 1024 + gsw0); \
    bt[j][1] = LD8(BUFB(S), brow + (j + 2) * 1024 + gsw1); } } while (0)
#define RD_B01(S, DST) do { _Pragma("unroll") for (int j = 0; j < 2; ++j) { \
    DST[j][0] = LD8(BUFB(S), brow + j * 1024 + gsw0); \
    DST[j][1] = LD8(BUFB(S), brow + j * 1024 + gsw1); } } while (0)

#define QUAD(AR, BR, IO, JO) do { \
    __builtin_amdgcn_s_setprio(1); \
    _Pragma("unroll") for (int i = 0; i < 4; ++i) \
    _Pragma("unroll") for (int j = 0; j < 2; ++j) { \
      acc[i + IO][j + JO] = __builtin_amdgcn_mfma_f32_16x16x32_bf16(AR[i][0], BR[j][0], acc[i + IO][j + JO], 0, 0, 0); \
      acc[i + IO][j + JO] = __builtin_amdgcn_mfma_f32_16x16x32_bf16(AR[i][1], BR[j][1], acc[i + IO][j + JO], 0, 0, 0); \
    } \
    __builtin_amdgcn_s_setprio(0); } while (0)

#define TILE(S, BCUR, BNXT, KT) do { \
    /* P0: read b23(t); stage B0(t+2); MFMA Q00 = aA x BCUR */ \
    RD_B23(S); \
    STAGE2(gB, sBb, (KT) + 2, 0, S); \
    SB0(); BAR(); LGKM4(); SB0(); \
    QUAD(aA, BCUR, 0, 0); \
    SB0(); BAR(); \
    /* P1: read a47(t); stage A0(t+2); MFMA Q01 = aA x bt; COUNTED DRAIN */ \
    RD_A47(S); \
    STAGE2(gA, sAb, (KT) + 2, 0, S); \
    SB0(); BAR(); LGKM8(); SB0(); \
    QUAD(aA, bt, 0, 2); \
    if ((KT) < NT - 2) asm volatile("s_waitcnt vmcnt(4)" ::: "memory"); \
    else               asm volatile("s_waitcnt vmcnt(0)" ::: "memory"); \
    SB0(); BAR(); \
    /* P2: read a03(t+1) -- now covered by P1's drain; stage B1(t+2); Q11 */ \
    RD_A03((S) ^ 1); \
    STAGE2(gB, sBb, (KT) + 2, 1, S); \
    SB0(); BAR(); LGKM8(); SB0(); \
    QUAD(aB, bt, 4, 2); \
    SB0(); BAR(); \
    /* P3: read b01(t+1)->BNXT; stage A1(t+2); MFMA Q10 = aB x BCUR */ \
    RD_B01((S) ^ 1, BNXT); \
    STAGE2(gA, sAb, (KT) + 2, 1, S); \
    SB0(); BAR(); LGKM4(); SB0(); \
    QUAD(aB, BCUR, 4, 0); \
    SB0(); BAR(); } while (0)

  // prologue: stage tiles 0 and 1 (16 loads); drain tile 0; pre-read
  STAGE2(gB, sBb, 0, 0, 0); STAGE2(gA, sAb, 0, 0, 0);
  STAGE2(gB, sBb, 0, 1, 0); STAGE2(gA, sAb, 0, 1, 0);
  STAGE2(gB, sBb, 1, 0, 1); STAGE2(gA, sAb, 1, 0, 1);
  STAGE2(gB, sBb, 1, 1, 1); STAGE2(gA, sAb, 1, 1, 1);
  asm volatile("s_waitcnt vmcnt(8)" ::: "memory");
  BAR();
  RD_A03(0);
  RD_B01(0, be);
  SB0();

#pragma unroll 1
  for (int it = 0; it < NT / 2; ++it) {
    const int kt0 = it * 2;
    TILE(0, be, bo, kt0);
    TILE(1, bo, be, kt0 + 1);
  }

  // epilogue: dt = h @ W2^T + b2 (rank-64), out = acc*dt + Dp
  bf16x8 wb0[4], wb1[4];
  float b2v[4], dpv[4];
#pragma unroll
  for (int j = 0; j < 4; ++j) {
    int n = n0 + wn * 64 + j * 16 + lm;
    const u16x8* wp = (const u16x8*)(w2bf + (size_t)n * R + lk * 8);
    wb0[j] = __builtin_bit_cast(bf16x8, wp[0]);
    wb1[j] = __builtin_bit_cast(bf16x8, wp[4]);  // +32 bf16
    b2v[j] = b2[n];
    dpv[j] = dp[n];
  }
#pragma unroll
  for (int mi = 0; mi < 8; ++mi) {
    int hrow = m0 + wm * 128 + mi * 16 + lm;
    const u16x8* hp = (const u16x8*)(hbf + (size_t)hrow * R + lk * 8);
    bf16x8 ha0 = __builtin_bit_cast(bf16x8, hp[0]);
    bf16x8 ha1 = __builtin_bit_cast(bf16x8, hp[4]);
    int mbase = m0 + wm * 128 + mi * 16 + lk * 4;
#pragma unroll
    for (int j = 0; j < 4; ++j) {
      f32x4 dt = {};
      dt = __builtin_amdgcn_mfma_f32_16x16x32_bf16(ha0, wb0[j], dt, 0, 0, 0);
      dt = __builtin_amdgcn_mfma_f32_16x16x32_bf16(ha1, wb1[j], dt, 0, 0, 0);
      int n = n0 + wn * 64 + j * 16 + lm;
#pragma unroll
      for (int r = 0; r < 4; ++r) {
        float val = acc[mi][j][r] * (dt[r] + b2v[j]) + dpv[j];
        out[(size_t)(mbase + r) * D + n] = val;
      }
    }
  }
#undef TILE
#undef QUAD
#undef RD_A03
#undef RD_A47
#undef RD_B23
#undef RD_B01
#undef STAGE2
#undef LGKM4
#undef LGKM8
#undef BAR
#undef SB0
#undef LD8
#undef BUFA
#undef BUFB
}

extern "C" void kernel_launch(void* const* d_in, const int* in_sizes, int n_in,
                              void* d_out, int out_size, void* d_ws, size_t ws_size,
                              hipStream_t stream) {
  const float* x  = (const float*)d_in[0];
  const float* A  = (const float*)d_in[1];
  const float* B  = (const float*)d_in[2];
  const float* C  = (const float*)d_in[3];
  const float* Dp = (const float*)d_in[4];
  const float* W1 = (const float*)d_in[5];
  const float* b1 = (const float*)d_in[6];
  const float* W2 = (const float*)d_in[7];
  const float* b2 = (const float*)d_in[8];
  float* out = (float*)d_out;

  uint8_t* ws = (uint8_t*)d_ws;
  unsigned short* xbf  = (unsigned short*)ws;                                // 32 MB
  unsigned short* st   = (unsigned short*)(ws + (32u << 20));                // 8 MB
  unsigned short* w2bf = (unsigned short*)(ws + (40u << 20));                // 256 KB
  unsigned short* hbf  = (unsigned short*)(ws + (41u << 20));                // 1 MB

  prep_kernel<<<772, 512, 0, stream>>>(x, A, B, C, W1, b1, W2, xbf, st, w2bf, hbf);
  gemm_kernel<<<256, 512, 0, stream>>>(xbf, st, hbf, w2bf, b2, Dp, out);
}